// Round 9
// baseline (298.955 us; speedup 1.0000x reference)
//
#include <hip/hip_runtime.h>
#include <hip/hip_cooperative_groups.h>
#include <math.h>
#include <stdint.h>

namespace cg = cooperative_groups;

#define D 512
#define H 500
#define NSPAN 256
#define KCON 1024
#define L 64

typedef __attribute__((ext_vector_type(8))) short short8;
typedef __attribute__((ext_vector_type(4))) float floatx4;

__device__ __forceinline__ short f2bf(float f) {   // RNE f32->bf16
    unsigned u = __builtin_bit_cast(unsigned, f);
    return (short)((u + 0x7fffu + ((u >> 16) & 1u)) >> 16);
}

struct SharedMem {
    union {
        struct {                       // phase 2 (fused scores)
            short Asw[16 * 2048];      // 64 KB: kb*2048 + mt*512 + m*32 + k
            float red[8][64];
            float sscore[64];
            float p[L + 1];
            int idx[L];
            float4 partb[4][128];
        } f;
        struct {                       // phase 1 (mm1)
            short Asw[16 * 512];       // 16 KB
        } m;
    } u;
};

__global__ void __launch_bounds__(512) k_all(
    const float* __restrict__ span, const float* __restrict__ know,
    const int* __restrict__ s2c, const int* __restrict__ lengths,
    const float* __restrict__ Ws, const float* __restrict__ bs,
    const float* __restrict__ W1, const float* __restrict__ b1,
    const float* __restrict__ W2, const float* __restrict__ b2,
    const float* __restrict__ W3, const float* __restrict__ b3,
    float* __restrict__ spanb1, float* __restrict__ parts,
    float* __restrict__ sentinel,
    short* __restrict__ W2bf, short* __restrict__ Wsbf,
    short* __restrict__ W1abf, short* __restrict__ W1bbf,
    float* __restrict__ out_features, float* __restrict__ out_probs) {
    cg::grid_group grid = cg::this_grid();
    __shared__ SharedMem sh;
    int b = blockIdx.x, tid = threadIdx.x;
    int wv = tid >> 6, ln = tid & 63;
    int nl = ln & 15, kq = ln >> 4;

    // ================= Phase 0: weight swizzles (bf16 B-frag) ==============
    // Slot s: B[k0..k0+7][n], kq=s&3, n=(s>>2)&511, kb=s>>11. mb: 0=W2,1=Ws,
    // 2=W1a, 3=W1b.
    {
        int mb = b >> 6;
        int s = (b & 63) * 512 + tid;
        int skq = s & 3, n = (s >> 2) & 511, kb = s >> 11;
        int k0 = kb * 32 + skq * 8;
        short8 v8;
        #pragma unroll
        for (int i = 0; i < 8; ++i) {
            int k = k0 + i;
            float v;
            if (mb == 0)      v = (k < H && n < H) ? W2[k * H + n] : 0.f;
            else if (mb == 1) v = Ws[k * D + n];
            else if (mb == 2) v = (n < H) ? W1[k * H + n] : 0.f;
            else              v = (n < H) ? W1[(D + k) * H + n] : 0.f;
            v8[i] = f2bf(v);
        }
        short* dst = (mb == 0) ? W2bf : (mb == 1) ? Wsbf : (mb == 2) ? W1abf : W1bbf;
        ((short8*)dst)[s] = v8;
    }
    __threadfence();
    grid.sync();

    // ================= Phase 1: parts GEMMs + sentinel chain ===============
    if (b < 176) {
        short* Asw = sh.u.m.Asw;
        const float* src;
        int rg, nh = 0, mode;          // 0=span,1=know,2=sentinel
        if (b < 32) { mode = 0; rg = b >> 1; nh = b & 1; src = span + rg * 16 * D; }
        else if (b < 160) { mode = 1; int bb = b - 32; rg = bb >> 1; nh = bb & 1;
                            src = know + rg * 16 * D; }
        else { mode = 2; rg = b - 160; src = span + rg * 16 * D; }

        {   // stage A: 16 rows x 512 k; thread = (row r, 16-k chunk kh)
            int r = tid >> 5, kh = tid & 31;
            const float4* sp = (const float4*)(src + r * D + kh * 16);
            short* dst = &Asw[(kh >> 1) * 512 + r * 32 + (kh & 1) * 16];
            #pragma unroll
            for (int g = 0; g < 4; ++g) {
                float4 a = sp[g];
                short4 o = {f2bf(a.x), f2bf(a.y), f2bf(a.z), f2bf(a.w)};
                ((short4*)dst)[g] = o;
            }
        }
        __syncthreads();
        int aoff = nl * 32 + kq * 8;

        if (mode < 2) {       // ---- span / know: 16 rows x 256 cols ----
            const short8* B = (const short8*)((mode == 0) ? W1abf : W1bbf);
            int tb = nh * 16 + wv * 2;
            int boff = tb * 64 + nl * 4 + kq;
            floatx4 acc[2];
            acc[0] = (floatx4){0.f, 0.f, 0.f, 0.f};
            acc[1] = acc[0];
            #pragma unroll 1
            for (int kb = 0; kb < 16; ++kb) {
                short8 a = *(const short8*)&Asw[kb * 512 + aoff];
                short8 bf0 = B[kb * 2048 + boff];
                short8 bf1 = B[kb * 2048 + boff + 64];
                acc[0] = __builtin_amdgcn_mfma_f32_16x16x32_bf16(a, bf0, acc[0], 0, 0, 0);
                acc[1] = __builtin_amdgcn_mfma_f32_16x16x32_bf16(a, bf1, acc[1], 0, 0, 0);
            }
            #pragma unroll
            for (int t = 0; t < 2; ++t) {
                int col = (tb + t) * 16 + nl;
                if (col < H) {
                    if (mode == 0) {
                        float bc = b1[col];
                        #pragma unroll
                        for (int r = 0; r < 4; ++r)
                            spanb1[(size_t)(rg * 16 + kq * 4 + r) * H + col] = acc[t][r] + bc;
                    } else {
                        #pragma unroll
                        for (int r = 0; r < 4; ++r)
                            parts[(size_t)(rg * 16 + kq * 4 + r) * H + col] = acc[t][r];
                    }
                }
            }
        } else {              // ---- sentinel chain: 16 rows x 512 cols ----
            int boff = (wv * 4) * 64 + nl * 4 + kq;
            floatx4 acc[4];
            #pragma unroll
            for (int t = 0; t < 4; ++t) acc[t] = (floatx4){0.f, 0.f, 0.f, 0.f};
            const short8* B1 = (const short8*)Wsbf;
            #pragma unroll 1
            for (int kb = 0; kb < 16; ++kb) {
                short8 a = *(const short8*)&Asw[kb * 512 + aoff];
                short8 bf[4];
                #pragma unroll
                for (int t = 0; t < 4; ++t) bf[t] = B1[kb * 2048 + boff + t * 64];
                #pragma unroll
                for (int t = 0; t < 4; ++t)
                    acc[t] = __builtin_amdgcn_mfma_f32_16x16x32_bf16(a, bf[t], acc[t], 0, 0, 0);
            }
            float vbuf[4][4];
            #pragma unroll
            for (int t = 0; t < 4; ++t) {
                int col = (wv * 4 + t) * 16 + nl;
                float bc = bs[col];
                #pragma unroll
                for (int r = 0; r < 4; ++r) {
                    float v = fmaxf(acc[t][r] + bc, 0.f);
                    vbuf[t][r] = v;
                    sentinel[(size_t)(rg * 16 + kq * 4 + r) * D + col] = v;
                }
            }
            __syncthreads();          // Asw stage-1 reads done
            #pragma unroll
            for (int t = 0; t < 4; ++t) {
                int col = (wv * 4 + t) * 16 + nl;
                short* d = &Asw[(col >> 5) * 512 + (col & 31)];
                #pragma unroll
                for (int r = 0; r < 4; ++r) d[(kq * 4 + r) * 32] = f2bf(vbuf[t][r]);
            }
            __syncthreads();
            const short8* B2 = (const short8*)W1bbf;
            #pragma unroll
            for (int t = 0; t < 4; ++t) acc[t] = (floatx4){0.f, 0.f, 0.f, 0.f};
            #pragma unroll 1
            for (int kb = 0; kb < 16; ++kb) {
                short8 a = *(const short8*)&Asw[kb * 512 + aoff];
                short8 bf[4];
                #pragma unroll
                for (int t = 0; t < 4; ++t) bf[t] = B2[kb * 2048 + boff + t * 64];
                #pragma unroll
                for (int t = 0; t < 4; ++t)
                    acc[t] = __builtin_amdgcn_mfma_f32_16x16x32_bf16(a, bf[t], acc[t], 0, 0, 0);
            }
            #pragma unroll
            for (int t = 0; t < 4; ++t) {
                int col = (wv * 4 + t) * 16 + nl;
                if (col < H) {
                    #pragma unroll
                    for (int r = 0; r < 4; ++r)
                        parts[(size_t)(KCON + rg * 16 + kq * 4 + r) * H + col] = acc[t][r];
                }
            }
        }
    }
    __threadfence();
    grid.sync();

    // ========== Phase 2: per-span scores + softmax + feature gather ========
    {
        int n = b;
        int V = lengths[n];
        V = (V < 1) ? 1 : ((V > 63) ? 63 : V);
        int R = V + 1;
        int nmt = (R + 15) >> 4;

        short* Asw = sh.u.f.Asw;
        if (tid < L) sh.u.f.idx[tid] = s2c[n * L + tid];

        {   // stage h1 rows -> A-frag LDS; thread = (row r: 32, k-panel kb: 16)
            int r = tid >> 4, kb = tid & 15, k0 = kb * 32;
            const float* spn = spanb1 + (size_t)n * H;
            #pragma unroll
            for (int half = 0; half < 2; ++half) {
                int rr = r + half * 32;
                if (rr < nmt * 16) {
                    int mt = rr >> 4, m = rr & 15;
                    short* dst = &Asw[kb * 2048 + mt * 512 + m * 32];
                    if (rr < R) {
                        const float* src = (rr < V)
                            ? parts + (size_t)s2c[n * L + rr] * H
                            : parts + (size_t)(KCON + n) * H;
                        const float4* s4 = (const float4*)(spn + k0);
                        const float4* r4 = (const float4*)(src + k0);
                        #pragma unroll
                        for (int g = 0; g < 8; ++g) {
                            if (k0 + g * 4 < H) {
                                float4 a = s4[g], c = r4[g];
                                dst[g * 4 + 0] = f2bf(fmaxf(a.x + c.x, 0.f));
                                dst[g * 4 + 1] = f2bf(fmaxf(a.y + c.y, 0.f));
                                dst[g * 4 + 2] = f2bf(fmaxf(a.z + c.z, 0.f));
                                dst[g * 4 + 3] = f2bf(fmaxf(a.w + c.w, 0.f));
                            } else {
                                *(short4*)&dst[g * 4] = (short4){0, 0, 0, 0};
                            }
                        }
                    } else {
                        #pragma unroll
                        for (int g = 0; g < 8; ++g)
                            *(short4*)&dst[g * 4] = (short4){0, 0, 0, 0};
                    }
                }
            }
        }
        __syncthreads();

        int aoffb = nl * 32 + kq * 8;
        int boffb = wv * 4 * 64 + nl * 4 + kq;   // wave owns a 64-col slab
        floatx4 acc[4][4];
        #pragma unroll
        for (int mt = 0; mt < 4; ++mt)
            #pragma unroll
            for (int t = 0; t < 4; ++t) acc[mt][t] = (floatx4){0.f, 0.f, 0.f, 0.f};

        const short8* B = (const short8*)W2bf;
        #pragma unroll 1
        for (int kb = 0; kb < 16; ++kb) {
            short8 bfr[4];
            #pragma unroll
            for (int t = 0; t < 4; ++t) bfr[t] = B[kb * 2048 + boffb + t * 64];
            #pragma unroll
            for (int mt = 0; mt < 4; ++mt) {
                if (mt < nmt) {
                    short8 a = *(const short8*)&Asw[kb * 2048 + mt * 512 + aoffb];
                    #pragma unroll
                    for (int t = 0; t < 4; ++t)
                        acc[mt][t] = __builtin_amdgcn_mfma_f32_16x16x32_bf16(a, bfr[t], acc[mt][t], 0, 0, 0);
                }
            }
        }

        float b2c[4], w3c[4];
        #pragma unroll
        for (int t = 0; t < 4; ++t) {
            int col = wv * 64 + t * 16 + nl;
            b2c[t] = (col < H) ? b2[col] : 0.f;
            w3c[t] = (col < H) ? W3[col] : 0.f;
        }
        #pragma unroll
        for (int mt = 0; mt < 4; ++mt) {
            if (mt < nmt) {
                #pragma unroll
                for (int r = 0; r < 4; ++r) {
                    float v = fmaxf(acc[mt][0][r] + b2c[0], 0.f) * w3c[0]
                            + fmaxf(acc[mt][1][r] + b2c[1], 0.f) * w3c[1]
                            + fmaxf(acc[mt][2][r] + b2c[2], 0.f) * w3c[2]
                            + fmaxf(acc[mt][3][r] + b2c[3], 0.f) * w3c[3];
                    v += __shfl_xor(v, 1, 64);
                    v += __shfl_xor(v, 2, 64);
                    v += __shfl_xor(v, 4, 64);
                    v += __shfl_xor(v, 8, 64);
                    if (nl == 0) sh.u.f.red[wv][mt * 16 + kq * 4 + r] = v;
                }
            }
        }
        __syncthreads();
        if (tid < R) {
            float s = b3[0];
            #pragma unroll
            for (int w = 0; w < 8; ++w) s += sh.u.f.red[w][tid];
            sh.u.f.sscore[tid] = s;
        }
        __syncthreads();

        if (tid < 64) {   // wave-parallel masked softmax (sentinel at [V])
            float sV = sh.u.f.sscore[V];
            float val = (tid < V) ? sh.u.f.sscore[tid] : -1e30f;
            float m = val;
            #pragma unroll
            for (int off = 32; off > 0; off >>= 1) m = fmaxf(m, __shfl_xor(m, off, 64));
            m = fmaxf(m, sV);
            float e = (tid < V) ? expf(val - m) : 0.f;
            float s = e;
            #pragma unroll
            for (int off = 32; off > 0; off >>= 1) s += __shfl_xor(s, off, 64);
            float eL = expf(sV - m);
            float inv = 1.f / (s + eL);
            sh.u.f.p[tid] = e * inv;
            if (tid == 0) sh.u.f.p[L] = eL * inv;
        }
        __syncthreads();
        if (tid <= L) out_probs[n * (L + 1) + tid] = sh.u.f.p[tid];

        // feature gather: 4 l-groups x 128 float4-cols
        int sub = tid >> 7, c = tid & 127;
        float4 acc4 = {0.f, 0.f, 0.f, 0.f};
        if (sub == 0) {
            float ps = sh.u.f.p[L];
            float4 sv = ((const float4*)sentinel)[n * 128 + c];
            acc4.x = ps * sv.x; acc4.y = ps * sv.y;
            acc4.z = ps * sv.z; acc4.w = ps * sv.w;
        }
        const float4* kn = (const float4*)know;
        for (int l = sub; l < V; l += 4) {
            float pl = sh.u.f.p[l];
            float4 v = kn[sh.u.f.idx[l] * 128 + c];
            acc4.x = fmaf(pl, v.x, acc4.x); acc4.y = fmaf(pl, v.y, acc4.y);
            acc4.z = fmaf(pl, v.z, acc4.z); acc4.w = fmaf(pl, v.w, acc4.w);
        }
        sh.u.f.partb[sub][c] = acc4;
        __syncthreads();
        if (tid < 128) {
            float4 a0 = sh.u.f.partb[0][tid], a1 = sh.u.f.partb[1][tid];
            float4 a2 = sh.u.f.partb[2][tid], a3 = sh.u.f.partb[3][tid];
            float4 o;
            o.x = a0.x + a1.x + a2.x + a3.x;
            o.y = a0.y + a1.y + a2.y + a3.y;
            o.z = a0.z + a1.z + a2.z + a3.z;
            o.w = a0.w + a1.w + a2.w + a3.w;
            ((float4*)out_features)[n * 128 + tid] = o;
        }
    }
}

extern "C" void kernel_launch(void* const* d_in, const int* in_sizes, int n_in,
                              void* d_out, int out_size, void* d_ws, size_t ws_size,
                              hipStream_t stream) {
    const float* span = (const float*)d_in[0];   // (256, 512)
    const float* know = (const float*)d_in[1];   // (1024, 512)
    const int* s2c = (const int*)d_in[2];        // (256, 64)
    const int* lengths = (const int*)d_in[3];    // (256,)
    const float* Ws = (const float*)d_in[4];     // (512, 512)
    const float* bs = (const float*)d_in[5];     // (512,)
    const float* W1 = (const float*)d_in[6];     // (1024, 500)
    const float* b1 = (const float*)d_in[7];     // (500,)
    const float* W2 = (const float*)d_in[8];     // (500, 500)
    const float* b2 = (const float*)d_in[9];     // (500,)
    const float* W3 = (const float*)d_in[10];    // (500, 1)
    const float* b3 = (const float*)d_in[11];    // (1,)

    float* wsp = (float*)d_ws;
    float* spanb1 = wsp;                              // 256*500
    float* parts = spanb1 + NSPAN * H;                // 1280*500 (know | sent)
    float* sentinel = parts + (KCON + NSPAN) * H;     // 256*512
    short* W2bf = (short*)(((uintptr_t)(sentinel + NSPAN * D) + 63) & ~(uintptr_t)63);
    short* Wsbf = W2bf + 512 * 512;
    short* W1abf = Wsbf + 512 * 512;
    short* W1bbf = W1abf + 512 * 512;

    float* out_features = (float*)d_out;              // 256*512
    float* out_probs = out_features + NSPAN * D;      // 256*65

    void* args[] = {
        (void*)&span, (void*)&know, (void*)&s2c, (void*)&lengths,
        (void*)&Ws, (void*)&bs, (void*)&W1, (void*)&b1,
        (void*)&W2, (void*)&b2, (void*)&W3, (void*)&b3,
        (void*)&spanb1, (void*)&parts, (void*)&sentinel,
        (void*)&W2bf, (void*)&Wsbf, (void*)&W1abf, (void*)&W1bbf,
        (void*)&out_features, (void*)&out_probs,
    };
    hipLaunchCooperativeKernel((void*)k_all, dim3(NSPAN), dim3(512), args, 0,
                               stream);
}

// Round 10
// 125.246 us; speedup vs baseline: 2.3869x; 2.3869x over previous
//
#include <hip/hip_runtime.h>
#include <math.h>
#include <stdint.h>

#define D 512
#define H 500
#define NSPAN 256
#define KCON 1024
#define L 64

typedef __attribute__((ext_vector_type(8))) short short8;
typedef __attribute__((ext_vector_type(4))) float floatx4;

__device__ __forceinline__ short f2bf(float f) {   // RNE f32->bf16
    unsigned u = __builtin_bit_cast(unsigned, f);
    return (short)((u + 0x7fffu + ((u >> 16) & 1u)) >> 16);
}

// ------- Kernel 0: Ws/W1a/W1b swizzles into bf16 B-frag layout -------------
// Slot s holds B[k0..k0+7][n], kq=s&3, n=(s>>2)&511, kb=s>>11, k0=kb*32+kq*8.
// b>>6 selects: 0=Ws, 1=W1a, 2=W1b.  (W2 swizzle lives in k_mm1.)
__global__ __launch_bounds__(512) void k_prep(
    const float* __restrict__ Ws, const float* __restrict__ W1,
    short* __restrict__ Wsbf, short* __restrict__ W1abf,
    short* __restrict__ W1bbf) {
    int b = blockIdx.x, tid = threadIdx.x;
    int mb = b >> 6;
    int s = (b & 63) * 512 + tid;
    int kq = s & 3, n = (s >> 2) & 511, kb = s >> 11;
    int k0 = kb * 32 + kq * 8;
    short8 v8;
    #pragma unroll
    for (int i = 0; i < 8; ++i) {
        int k = k0 + i;
        float v;
        if (mb == 0)      v = Ws[k * D + n];
        else if (mb == 1) v = (n < H) ? W1[k * H + n] : 0.f;
        else              v = (n < H) ? W1[(D + k) * H + n] : 0.f;
        v8[i] = f2bf(v);
    }
    short* dst = (mb == 0) ? Wsbf : (mb == 1) ? W1abf : W1bbf;
    ((short8*)dst)[s] = v8;
}

// ------- Kernel 1: MFMA parts GEMMs + sentinel chain + W2 swizzle ----------
// 304 blocks x 256 thr. b<32: span@W1a+b1 (16 rows x half-N); b<160:
// know@W1b; b<176: sentinel chain; b>=176: W2 -> bf16 B-frag swizzle
// (consumed by the NEXT kernel only).
__global__ __launch_bounds__(256) void k_mm1(
    const float* __restrict__ span, const float* __restrict__ know,
    const float* __restrict__ bs, const float* __restrict__ b1,
    const float* __restrict__ W2,
    const short* __restrict__ Wsbf, const short* __restrict__ W1abf,
    const short* __restrict__ W1bbf,
    float* __restrict__ spanb1, float* __restrict__ parts,
    float* __restrict__ sentinel, short* __restrict__ W2bf) {
    __shared__ __align__(16) short Asw[16 * 512];   // 16 KB
    int b = blockIdx.x, tid = threadIdx.x;

    if (b >= 176) {   // ---- W2 swizzle: 128 blocks x 256 slots ----
        int s = (b - 176) * 256 + tid;          // [0, 32768)
        int kq = s & 3, n = (s >> 2) & 511, kb = s >> 11;
        int k0 = kb * 32 + kq * 8;
        short8 v8;
        #pragma unroll
        for (int i = 0; i < 8; ++i) {
            int k = k0 + i;
            float v = (k < H && n < H) ? W2[k * H + n] : 0.f;
            v8[i] = f2bf(v);
        }
        ((short8*)W2bf)[s] = v8;
        return;
    }

    int wv = tid >> 6, ln = tid & 63;
    int nl = ln & 15, kq = ln >> 4;
    int aoff = nl * 32 + kq * 8;

    if (b < 160) {            // ---- span / know: 16 rows x 256 cols ----
        int rg, nh;
        const float* src;
        const short8* B;
        bool is_span = (b < 32);
        if (is_span) { rg = b >> 1; nh = b & 1; src = span + rg * 16 * D;
                       B = (const short8*)W1abf; }
        else { int bb = b - 32; rg = bb >> 1; nh = bb & 1; src = know + rg * 16 * D;
               B = (const short8*)W1bbf; }
        {   // stage A: thread = (row r, k-panel kb), 32 contiguous bf16
            int r = tid >> 4, kb = tid & 15;
            const float* sp = src + r * D + kb * 32;
            short* dst = &Asw[kb * 512 + r * 32];
            #pragma unroll
            for (int i = 0; i < 32; ++i) dst[i] = f2bf(sp[i]);
        }
        __syncthreads();
        floatx4 acc[4];
        #pragma unroll
        for (int t = 0; t < 4; ++t) acc[t] = (floatx4){0.f, 0.f, 0.f, 0.f};
        int tb = nh * 16 + wv * 4;
        int boff = tb * 64 + nl * 4 + kq;
        short8 bcur[4], bnxt[4];
        #pragma unroll
        for (int t = 0; t < 4; ++t) bcur[t] = B[boff + t * 64];
        #pragma unroll 1
        for (int kb = 0; kb < 16; ++kb) {
            int kn = (kb + 1) & 15;
            #pragma unroll
            for (int t = 0; t < 4; ++t) bnxt[t] = B[kn * 2048 + boff + t * 64];
            short8 a = *(const short8*)&Asw[kb * 512 + aoff];
            #pragma unroll
            for (int t = 0; t < 4; ++t)
                acc[t] = __builtin_amdgcn_mfma_f32_16x16x32_bf16(a, bcur[t], acc[t], 0, 0, 0);
            #pragma unroll
            for (int t = 0; t < 4; ++t) bcur[t] = bnxt[t];
        }
        #pragma unroll
        for (int t = 0; t < 4; ++t) {
            int col = (tb + t) * 16 + nl;
            if (col < H) {
                if (is_span) {
                    float bc = b1[col];
                    #pragma unroll
                    for (int r = 0; r < 4; ++r)
                        spanb1[(size_t)(rg * 16 + kq * 4 + r) * H + col] = acc[t][r] + bc;
                } else {
                    #pragma unroll
                    for (int r = 0; r < 4; ++r)
                        parts[(size_t)(rg * 16 + kq * 4 + r) * H + col] = acc[t][r];
                }
            }
        }
        return;
    }

    // ---- sentinel chain: 16 rows x full 512 cols, two chained GEMMs ----
    int rg = b - 160;
    const float* src = span + rg * 16 * D;
    {
        int r = tid >> 4, kb = tid & 15;
        const float* sp = src + r * D + kb * 32;
        short* dst = &Asw[kb * 512 + r * 32];
        #pragma unroll
        for (int i = 0; i < 32; ++i) dst[i] = f2bf(sp[i]);
    }
    __syncthreads();
    floatx4 acc[8];
    #pragma unroll
    for (int t = 0; t < 8; ++t) acc[t] = (floatx4){0.f, 0.f, 0.f, 0.f};
    int boff = wv * 8 * 64 + nl * 4 + kq;
    const short8* B1 = (const short8*)Wsbf;
    #pragma unroll 1
    for (int kb = 0; kb < 16; ++kb) {
        short8 a = *(const short8*)&Asw[kb * 512 + aoff];
        short8 bf[8];
        #pragma unroll
        for (int t = 0; t < 8; ++t) bf[t] = B1[kb * 2048 + boff + t * 64];
        #pragma unroll
        for (int t = 0; t < 8; ++t)
            acc[t] = __builtin_amdgcn_mfma_f32_16x16x32_bf16(a, bf[t], acc[t], 0, 0, 0);
    }
    float vbuf[8][4];
    #pragma unroll
    for (int t = 0; t < 8; ++t) {
        int col = (wv * 8 + t) * 16 + nl;
        float bc = bs[col];
        #pragma unroll
        for (int r = 0; r < 4; ++r) {
            float v = fmaxf(acc[t][r] + bc, 0.f);
            vbuf[t][r] = v;
            sentinel[(size_t)(rg * 16 + kq * 4 + r) * D + col] = v;
        }
    }
    __syncthreads();          // Asw stage-1 reads done
    #pragma unroll
    for (int t = 0; t < 8; ++t) {
        int col = (wv * 8 + t) * 16 + nl;
        short* d = &Asw[(col >> 5) * 512 + (col & 31)];
        #pragma unroll
        for (int r = 0; r < 4; ++r) d[(kq * 4 + r) * 32] = f2bf(vbuf[t][r]);
    }
    __syncthreads();
    const short8* B2 = (const short8*)W1bbf;
    #pragma unroll
    for (int t = 0; t < 8; ++t) acc[t] = (floatx4){0.f, 0.f, 0.f, 0.f};
    #pragma unroll 1
    for (int kb = 0; kb < 16; ++kb) {
        short8 a = *(const short8*)&Asw[kb * 512 + aoff];
        short8 bf[8];
        #pragma unroll
        for (int t = 0; t < 8; ++t) bf[t] = B2[kb * 2048 + boff + t * 64];
        #pragma unroll
        for (int t = 0; t < 8; ++t)
            acc[t] = __builtin_amdgcn_mfma_f32_16x16x32_bf16(a, bf[t], acc[t], 0, 0, 0);
    }
    #pragma unroll
    for (int t = 0; t < 8; ++t) {
        int col = (wv * 8 + t) * 16 + nl;
        if (col < H) {
            #pragma unroll
            for (int r = 0; r < 4; ++r)
                parts[(size_t)(KCON + rg * 16 + kq * 4 + r) * H + col] = acc[t][r];
        }
    }
}

// ---- Kernel 2: fused per-span scores + softmax + probs + feature gather ---
// grid 256 (1 span/block), 512 thr = 8 waves. R = V+1 <= 64 rows staged once
// (up to 4 M-tiles bf16 in LDS); W2bf streamed once per block with register
// double-buffered prefetch; epilogue (softmax + gather) in-block.
__global__ __launch_bounds__(512) void k_fused(
    const int* __restrict__ s2c, const int* __restrict__ lengths,
    const float* __restrict__ spanb1, const float* __restrict__ parts,
    const float* __restrict__ sentinel, const short* __restrict__ W2bf,
    const float* __restrict__ b2, const float* __restrict__ W3,
    const float* __restrict__ b3, const float* __restrict__ know,
    float* __restrict__ out_features, float* __restrict__ out_probs) {
    int n = blockIdx.x, tid = threadIdx.x;
    int V = lengths[n];
    V = (V < 1) ? 1 : ((V > 63) ? 63 : V);
    int R = V + 1;                 // concepts 0..V-1, sentinel at row V
    int nmt = (R + 15) >> 4;       // M-tiles (1..4)

    __shared__ __align__(16) short Asw[16 * 2048];   // 64 KB: kb*2048+mt*512+m*32+k
    __shared__ float red[8][64];
    __shared__ float sscore[64];
    __shared__ float p[L + 1];
    __shared__ int idx[L];
    __shared__ __align__(16) float4 partb[4][128];   // 8 KB

    if (tid < L) idx[tid] = s2c[n * L + tid];

    {   // stage h1 rows -> A-frag LDS; thread = (row r: 32, k-panel kb: 16)
        int r = tid >> 4, kb = tid & 15, k0 = kb * 32;
        const float* spn = spanb1 + (size_t)n * H;
        #pragma unroll
        for (int half = 0; half < 2; ++half) {
            int rr = r + half * 32;
            if (rr < nmt * 16) {
                int mt = rr >> 4, m = rr & 15;
                short* dst = &Asw[kb * 2048 + mt * 512 + m * 32];
                if (rr < R) {
                    const float* src = (rr < V)
                        ? parts + (size_t)s2c[n * L + rr] * H
                        : parts + (size_t)(KCON + n) * H;
                    const float4* s4 = (const float4*)(spn + k0);
                    const float4* r4 = (const float4*)(src + k0);
                    #pragma unroll
                    for (int g = 0; g < 8; ++g) {
                        if (k0 + g * 4 < H) {     // 500 = 125 float4, clean split
                            float4 a = s4[g], c = r4[g];
                            dst[g * 4 + 0] = f2bf(fmaxf(a.x + c.x, 0.f));
                            dst[g * 4 + 1] = f2bf(fmaxf(a.y + c.y, 0.f));
                            dst[g * 4 + 2] = f2bf(fmaxf(a.z + c.z, 0.f));
                            dst[g * 4 + 3] = f2bf(fmaxf(a.w + c.w, 0.f));
                        } else {
                            *(short4*)&dst[g * 4] = (short4){0, 0, 0, 0};
                        }
                    }
                } else {
                    #pragma unroll
                    for (int g = 0; g < 8; ++g)
                        *(short4*)&dst[g * 4] = (short4){0, 0, 0, 0};
                }
            }
        }
    }
    __syncthreads();

    int wv = tid >> 6, ln = tid & 63;
    int nl = ln & 15, kq = ln >> 4;
    int aoffb = nl * 32 + kq * 8;
    int boffb = wv * 4 * 64 + nl * 4 + kq;   // wave owns a 64-col slab
    floatx4 acc[4][4];
    #pragma unroll
    for (int mt = 0; mt < 4; ++mt)
        #pragma unroll
        for (int t = 0; t < 4; ++t) acc[mt][t] = (floatx4){0.f, 0.f, 0.f, 0.f};

    const short8* B = (const short8*)W2bf;
    short8 bcur[4], bnxt[4];
    #pragma unroll
    for (int t = 0; t < 4; ++t) bcur[t] = B[boffb + t * 64];
    #pragma unroll 1
    for (int kb = 0; kb < 16; ++kb) {
        int kn = (kb + 1) & 15;
        #pragma unroll
        for (int t = 0; t < 4; ++t) bnxt[t] = B[kn * 2048 + boffb + t * 64];
        #pragma unroll
        for (int mt = 0; mt < 4; ++mt) {
            if (mt < nmt) {
                short8 a = *(const short8*)&Asw[kb * 2048 + mt * 512 + aoffb];
                #pragma unroll
                for (int t = 0; t < 4; ++t)
                    acc[mt][t] = __builtin_amdgcn_mfma_f32_16x16x32_bf16(a, bcur[t], acc[mt][t], 0, 0, 0);
            }
        }
        #pragma unroll
        for (int t = 0; t < 4; ++t) bcur[t] = bnxt[t];
    }

    float b2c[4], w3c[4];
    #pragma unroll
    for (int t = 0; t < 4; ++t) {
        int col = wv * 64 + t * 16 + nl;
        b2c[t] = (col < H) ? b2[col] : 0.f;
        w3c[t] = (col < H) ? W3[col] : 0.f;
    }
    #pragma unroll
    for (int mt = 0; mt < 4; ++mt) {
        if (mt < nmt) {
            #pragma unroll
            for (int r = 0; r < 4; ++r) {
                float v = fmaxf(acc[mt][0][r] + b2c[0], 0.f) * w3c[0]
                        + fmaxf(acc[mt][1][r] + b2c[1], 0.f) * w3c[1]
                        + fmaxf(acc[mt][2][r] + b2c[2], 0.f) * w3c[2]
                        + fmaxf(acc[mt][3][r] + b2c[3], 0.f) * w3c[3];
                v += __shfl_xor(v, 1, 64);
                v += __shfl_xor(v, 2, 64);
                v += __shfl_xor(v, 4, 64);
                v += __shfl_xor(v, 8, 64);
                if (nl == 0) red[wv][mt * 16 + kq * 4 + r] = v;
            }
        }
    }
    __syncthreads();
    if (tid < R) {
        float s = b3[0];
        #pragma unroll
        for (int w = 0; w < 8; ++w) s += red[w][tid];
        sscore[tid] = s;
    }
    __syncthreads();

    if (tid < 64) {   // wave-parallel masked softmax (sentinel at sscore[V])
        float sV = sscore[V];
        float val = (tid < V) ? sscore[tid] : -1e30f;
        float m = val;
        #pragma unroll
        for (int off = 32; off > 0; off >>= 1) m = fmaxf(m, __shfl_xor(m, off, 64));
        m = fmaxf(m, sV);
        float e = (tid < V) ? expf(val - m) : 0.f;
        float s = e;
        #pragma unroll
        for (int off = 32; off > 0; off >>= 1) s += __shfl_xor(s, off, 64);
        float eL = expf(sV - m);
        float inv = 1.f / (s + eL);
        p[tid] = e * inv;
        if (tid == 0) p[L] = eL * inv;
    }
    __syncthreads();
    if (tid <= L) out_probs[n * (L + 1) + tid] = p[tid];

    // feature gather: 4 l-groups x 128 float4-cols
    int sub = tid >> 7, c = tid & 127;
    float4 acc4 = {0.f, 0.f, 0.f, 0.f};
    if (sub == 0) {
        float ps = p[L];
        float4 sv = ((const float4*)sentinel)[n * 128 + c];
        acc4.x = ps * sv.x; acc4.y = ps * sv.y; acc4.z = ps * sv.z; acc4.w = ps * sv.w;
    }
    const float4* kn = (const float4*)know;
    for (int l = sub; l < V; l += 4) {
        float pl = p[l];
        float4 v = kn[idx[l] * 128 + c];
        acc4.x = fmaf(pl, v.x, acc4.x); acc4.y = fmaf(pl, v.y, acc4.y);
        acc4.z = fmaf(pl, v.z, acc4.z); acc4.w = fmaf(pl, v.w, acc4.w);
    }
    partb[sub][c] = acc4;
    __syncthreads();
    if (tid < 128) {
        float4 a0 = partb[0][tid], a1 = partb[1][tid];
        float4 a2 = partb[2][tid], a3 = partb[3][tid];
        float4 o;
        o.x = a0.x + a1.x + a2.x + a3.x;
        o.y = a0.y + a1.y + a2.y + a3.y;
        o.z = a0.z + a1.z + a2.z + a3.z;
        o.w = a0.w + a1.w + a2.w + a3.w;
        ((float4*)out_features)[n * 128 + tid] = o;
    }
}

extern "C" void kernel_launch(void* const* d_in, const int* in_sizes, int n_in,
                              void* d_out, int out_size, void* d_ws, size_t ws_size,
                              hipStream_t stream) {
    const float* span = (const float*)d_in[0];   // (256, 512)
    const float* know = (const float*)d_in[1];   // (1024, 512)
    const int* s2c = (const int*)d_in[2];        // (256, 64)
    const int* lengths = (const int*)d_in[3];    // (256,)
    const float* Ws = (const float*)d_in[4];     // (512, 512)
    const float* bs = (const float*)d_in[5];     // (512,)
    const float* W1 = (const float*)d_in[6];     // (1024, 500)
    const float* b1 = (const float*)d_in[7];     // (500,)
    const float* W2 = (const float*)d_in[8];     // (500, 500)
    const float* b2 = (const float*)d_in[9];     // (500,)
    const float* W3 = (const float*)d_in[10];    // (500, 1)
    const float* b3 = (const float*)d_in[11];    // (1,)

    float* wsp = (float*)d_ws;
    float* spanb1 = wsp;                              // 256*500
    float* parts = spanb1 + NSPAN * H;                // 1280*500 (know | sent)
    float* sentinel = parts + (KCON + NSPAN) * H;     // 256*512
    short* W2bf = (short*)(((uintptr_t)(sentinel + NSPAN * D) + 63) & ~(uintptr_t)63);
    short* Wsbf = W2bf + 512 * 512;
    short* W1abf = Wsbf + 512 * 512;
    short* W1bbf = W1abf + 512 * 512;

    float* out_features = (float*)d_out;              // 256*512
    float* out_probs = out_features + NSPAN * D;      // 256*65

    k_prep<<<192, 512, 0, stream>>>(Ws, W1, Wsbf, W1abf, W1bbf);
    k_mm1<<<304, 256, 0, stream>>>(span, know, bs, b1, W2, Wsbf, W1abf, W1bbf,
                                   spanb1, parts, sentinel, W2bf);
    k_fused<<<NSPAN, 512, 0, stream>>>(s2c, lengths, spanb1, parts, sentinel,
                                       W2bf, b2, W3, b3, know,
                                       out_features, out_probs);
}